// Round 7
// baseline (29.748 us; speedup 1.0000x reference)
//
#include <hip/hip_runtime.h>

// Problem constants (from reference)
#define N_IDEAS 5
#define N_EXPERTS 10
#define OUT_DIM 784          // 28*28
#define CHUNKS 196           // OUT_DIM / 4 (float4 chunks per sample)
#define BATCH 32768
#define CTILE 28             // chunks per tile (196 = 7*28)
#define NTILES 7
#define SPB 128              // samples per block
#define BLOCK 256
#define KSLOT 9              // sample-slots per iteration (9*28 = 252 active)

// Block = (128-sample slab sg, 28-chunk tile ct). Sort the slab's samples by
// expert in LDS (order-independent -> deterministic). Per expert segment:
// each thread register-loads its chunk's W (5 float4) + b (1 float4) from
// L2-resident globals ONCE, then the per-sample inner loop is only:
// broadcast LDS reads (sorted id + 5 x floats) + 20 FMA + 1 dwordx4 store.
// Hot-loop LDS traffic: ~24 B per 16 B stored (was 120 B) -> store-BW bound.
__global__ __launch_bounds__(BLOCK) void moe_sorted(
    const float* __restrict__ x,      // [B, 5]
    const int* __restrict__ labels,   // [B]
    const float* __restrict__ W,      // [E, 784, 5]
    const float* __restrict__ b,      // [E, 784]
    float4* __restrict__ out)         // [B*196]
{
    __shared__ float xl[SPB * 8];        // 4 KB, stride-8 rows
    __shared__ int   ll[SPB];            // labels
    __shared__ int   sorted[SPB];        // sample ids grouped by expert
    __shared__ int   hcnt[N_EXPERTS];
    __shared__ int   hcur[N_EXPERTS];
    __shared__ int   seg[N_EXPERTS + 1];

    const int tid = threadIdx.x;
    const int sg  = blockIdx.x;          // sample slab [sg*128, +128)
    const int ct  = blockIdx.y;          // chunk tile  [ct*28, +28)

    // ---- staging: x slab (stride-8 scatter), labels; zero histogram ----
    if (tid < N_EXPERTS) hcnt[tid] = 0;
    if (tid < (SPB * N_IDEAS) / 4) {     // 160 float4
        const float4 v = ((const float4*)x)[(size_t)sg * ((SPB * N_IDEAS) / 4) + tid];
        const float vv[4] = {v.x, v.y, v.z, v.w};
        const int f0 = tid * 4;
#pragma unroll
        for (int j = 0; j < 4; ++j) {
            const int f = f0 + j;
            const int s = f / 5;
            xl[s * 8 + (f - s * 5)] = vv[j];
        }
    }
    if (tid < SPB / 4)
        ((int4*)ll)[tid] = ((const int4*)labels)[sg * (SPB / 4) + tid];
    __syncthreads();

    // ---- in-block counting sort by expert (output order-independent) ----
    if (tid < SPB) atomicAdd(&hcnt[ll[tid]], 1);
    __syncthreads();
    if (tid == 0) {
        int a = 0;
#pragma unroll
        for (int e = 0; e < N_EXPERTS; ++e) { seg[e] = a; hcur[e] = a; a += hcnt[e]; }
        seg[N_EXPERTS] = a;              // == SPB
    }
    __syncthreads();
    if (tid < SPB) {
        const int p = atomicAdd(&hcur[ll[tid]], 1);
        sorted[p] = tid;
    }
    __syncthreads();

    // ---- hot loop over expert segments ----
    const int k = tid / CTILE;           // sample slot 0..9 (k==9: store-idle)
    const int c = tid - k * CTILE;       // chunk within tile 0..27
    const bool active = (k < KSLOT);
    const int gc = ct * CTILE + c;       // global chunk 0..195
    const float4* Wg = (const float4*)W; // 980 f4 per expert
    const float4* bg = (const float4*)b; // 196 f4 per expert
    const size_t rowBase = (size_t)sg * SPB;

    for (int e = 0; e < N_EXPERTS; ++e) {
        const int s0 = seg[e], s1 = seg[e + 1];
        if (s0 == s1) continue;

        // W/b fragment for (e, gc): 6 x 16B from L2-resident globals
        const float4* wp = Wg + (size_t)e * 980 + (size_t)gc * 5;
        const float4 w0 = wp[0], w1 = wp[1], w2 = wp[2], w3 = wp[3], w4 = wp[4];
        const float4 bb = bg[e * 196 + gc];

        for (int j0 = s0; j0 < s1; j0 += KSLOT) {
            const int j  = j0 + k;
            const int jj = (j < s1) ? j : (s1 - 1);
            const int sid = sorted[jj];              // broadcast per 28-lane group
            const float* xp = &xl[sid * 8];          // broadcast reads
            const float x0 = xp[0], x1 = xp[1], x2 = xp[2], x3 = xp[3], x4 = xp[4];

            float4 r;
            r.x = bb.x + w0.x*x0 + w0.y*x1 + w0.z*x2 + w0.w*x3 + w1.x*x4;
            r.y = bb.y + w1.y*x0 + w1.z*x1 + w1.w*x2 + w2.x*x3 + w2.y*x4;
            r.z = bb.z + w2.z*x0 + w2.w*x1 + w3.x*x2 + w3.y*x3 + w3.z*x4;
            r.w = bb.w + w3.w*x0 + w4.x*x1 + w4.y*x2 + w4.z*x3 + w4.w*x4;

            if (active && j < s1)
                out[(rowBase + sid) * CHUNKS + gc] = r;
        }
    }
}

extern "C" void kernel_launch(void* const* d_in, const int* in_sizes, int n_in,
                              void* d_out, int out_size, void* d_ws, size_t ws_size,
                              hipStream_t stream) {
    const float* x      = (const float*)d_in[0];
    const int*   labels = (const int*)d_in[1];
    const float* W      = (const float*)d_in[2];
    const float* b      = (const float*)d_in[3];
    float4* out = (float4*)d_out;

    dim3 grid(BATCH / SPB, NTILES);      // 256 x 7 = 1792 blocks = 7/CU exact
    moe_sorted<<<grid, dim3(BLOCK), 0, stream>>>(x, labels, W, b, out);
}

// Round 8
// 28.203 us; speedup vs baseline: 1.0548x; 1.0548x over previous
//
#include <hip/hip_runtime.h>

// Problem constants (from reference)
#define N_IDEAS 5
#define N_EXPERTS 10
#define OUT_DIM 784          // 28*28
#define CHUNKS 196           // OUT_DIM / 4 (float4 chunks per sample)
#define BATCH 32768
#define CTILE 14             // chunks per tile (196 = 14*14)
#define NTILES 14
#define SPB 128              // samples per block
#define BLOCK 256
#define KSLOTS 18            // sample-slots per iter (18*14 = 252 active lanes)
#define NITER 8              // ceil(128*14 / 252)

// Balanced persistent-ish tiling: grid 256x14 = 3584 blocks = exactly 14/CU.
// LDS slimmed to ~16.5 KB -> 8 resident blocks/CU (32 waves, full occupancy),
// so per-block staging hides behind 7 other blocks' hot loops.
// Thread: fixed chunk c = tid%14, sample slot k = tid/14; per iter reads
// e (4B) + x (20B broadcast) + W (80B b128) + b (16B) from LDS, 20 FMA,
// one dwordx4 store; 18 rows x 224B sequential segments per iteration.
__global__ __launch_bounds__(BLOCK, 8) void moe_fused14(
    const float* __restrict__ x,      // [B, 5]
    const int* __restrict__ labels,   // [B]
    const float* __restrict__ W,      // [E, 784, 5]
    const float* __restrict__ b,      // [E, 784]
    float4* __restrict__ out)         // [B*196]
{
    __shared__ float4 Wl4[N_EXPERTS * CTILE * 5];   // 11.2 KB [e][c][5]
    __shared__ float4 bl4[N_EXPERTS * CTILE];       // 2.24 KB [e][c]
    __shared__ float4 xl4[(SPB * N_IDEAS) / 4];     // 2.56 KB, viewed as float[640]
    __shared__ int    ll[SPB];                      // 512 B

    float* xl = (float*)xl4;
    const int tid = threadIdx.x;
    const int sg  = blockIdx.x;          // sample slab [sg*128, +128)
    const int ct  = blockIdx.y;          // chunk tile  [ct*14, +14)

    // ---- one-time staging (~1030 float4 over 256 threads) ----
    {
        const float4* Wg = (const float4*)W;        // 980 f4 per expert
        for (int i = tid; i < N_EXPERTS * CTILE * 5; i += BLOCK) {  // 700
            const int e = i / 70, r = i - e * 70;   // 70 f4 per expert-tile
            Wl4[e * 70 + r] = Wg[e * 980 + ct * 70 + r];
        }
        const float4* bg = (const float4*)b;        // 196 f4 per expert
        for (int i = tid; i < N_EXPERTS * CTILE; i += BLOCK) {      // 140
            const int e = i / CTILE, r = i - e * CTILE;
            bl4[e * CTILE + r] = bg[e * 196 + ct * CTILE + r];
        }
        const float4* xg = (const float4*)x;
        if (tid < (SPB * N_IDEAS) / 4)                              // 160
            xl4[tid] = xg[(size_t)sg * ((SPB * N_IDEAS) / 4) + tid];
        if (tid < SPB / 4)                                          // 32
            ((int4*)ll)[tid] = ((const int4*)labels)[sg * (SPB / 4) + tid];
    }
    __syncthreads();

    // ---- hot loop ----
    const int k = tid / CTILE;           // sample slot 0..17 (k==18: idle 4 lanes)
    const int c = tid - k * CTILE;       // fixed chunk within tile, 0..13
    const bool lane_ok = (tid < KSLOTS * CTILE);
    const size_t outBase = (size_t)sg * SPB * CHUNKS + (size_t)ct * CTILE + c;

#pragma unroll
    for (int it = 0; it < NITER; ++it) {
        const int s = it * KSLOTS + k;   // local sample 0..143 (masked >=128)
        const bool act = lane_ok && (s < SPB);
        const int ss = act ? s : 0;      // clamp for safe LDS addressing

        const int e = ll[ss];
        const float* xp = &xl[ss * N_IDEAS];
        const float x0 = xp[0], x1 = xp[1], x2 = xp[2], x3 = xp[3], x4 = xp[4];

        const float4* wp = &Wl4[(e * CTILE + c) * 5];
        const float4 w0 = wp[0], w1 = wp[1], w2 = wp[2], w3 = wp[3], w4 = wp[4];
        const float4 bb = bl4[e * CTILE + c];

        float4 r;
        r.x = bb.x + w0.x*x0 + w0.y*x1 + w0.z*x2 + w0.w*x3 + w1.x*x4;
        r.y = bb.y + w1.y*x0 + w1.z*x1 + w1.w*x2 + w2.x*x3 + w2.y*x4;
        r.z = bb.z + w2.z*x0 + w2.w*x1 + w3.x*x2 + w3.y*x3 + w3.z*x4;
        r.w = bb.w + w3.w*x0 + w4.x*x1 + w4.y*x2 + w4.z*x3 + w4.w*x4;

        if (act)
            out[outBase + (size_t)s * CHUNKS] = r;   // 224B segments x 18 rows
    }
}

extern "C" void kernel_launch(void* const* d_in, const int* in_sizes, int n_in,
                              void* d_out, int out_size, void* d_ws, size_t ws_size,
                              hipStream_t stream) {
    const float* x      = (const float*)d_in[0];
    const int*   labels = (const int*)d_in[1];
    const float* W      = (const float*)d_in[2];
    const float* b      = (const float*)d_in[3];
    float4* out = (float4*)d_out;

    dim3 grid(BATCH / SPB, NTILES);      // 256 x 14 = 3584 blocks = 14/CU exact
    moe_fused14<<<grid, dim3(BLOCK), 0, stream>>>(x, labels, W, b, out);
}